// Round 16
// baseline (138.753 us; speedup 1.0000x reference)
//
#include <hip/hip_runtime.h>
#include <stdint.h>

#define B_ 4
#define T1_ 4096
#define T2_ 2048
#define C_ 512
#define H_ 8
#define D_ 64
#define M1_ (B_*T1_)   // 16384
#define M2_ (B_*T2_)   // 8192

using f32x4 = __attribute__((ext_vector_type(4))) float;
using bf16x8 = __attribute__((ext_vector_type(8))) __bf16;
using us8 = __attribute__((ext_vector_type(8))) unsigned short;
using us4 = __attribute__((ext_vector_type(4))) unsigned short;

__device__ __forceinline__ unsigned short f2bf(float f){
  unsigned int u = __builtin_bit_cast(unsigned int, f);
  unsigned int r = (u + 0x7fffu + ((u >> 16) & 1u)) >> 16;
  return (unsigned short)r;
}
__device__ __forceinline__ float bf2f(unsigned short u){
  return __builtin_bit_cast(float, ((unsigned int)u) << 16);
}
__device__ __forceinline__ f32x4 mfma16(us8 a, us8 b, f32x4 c){
  return __builtin_amdgcn_mfma_f32_16x16x32_bf16(
      __builtin_bit_cast(bf16x8, a), __builtin_bit_cast(bf16x8, b), c, 0, 0, 0);
}
// hot-path cvt: compiler emits packed v_cvt (m240: prefer cast over hand-asm)
__device__ __forceinline__ us8 cvt8(f32x4 a, f32x4 b){
  us8 v;
  #pragma unroll
  for (int j = 0; j < 4; ++j){
    v[j]   = __builtin_bit_cast(unsigned short, (__bf16)a[j]);
    v[4+j] = __builtin_bit_cast(unsigned short, (__bf16)b[j]);
  }
  return v;
}

typedef const __attribute__((address_space(1))) unsigned int gu32;
typedef __attribute__((address_space(3))) unsigned int lu32;
__device__ __forceinline__ void gl_lds16(const void* g, void* l){
  __builtin_amdgcn_global_load_lds((gu32*)g, (lu32*)l, 16, 0, 0);
}

#define WAIT_VM(N) asm volatile("s_waitcnt vmcnt(" #N ")" ::: "memory")
#define WAIT_LGKM() asm volatile("s_waitcnt lgkmcnt(0)" ::: "memory")
#define RAW_BAR()  { __builtin_amdgcn_s_barrier(); __builtin_amdgcn_sched_barrier(0); }

// chunk swizzle for the K-loop staging (involution, rule 21)
__device__ __forceinline__ int swz(int row, int blk){ return blk ^ ((row >> 1) & 3); }

// ---------------- fp32 -> bf16 convert (weights only) ----------------
__global__ __launch_bounds__(256) void cvt_bf16_4(const float* __restrict__ p0, const float* __restrict__ p1,
                                                  const float* __restrict__ p2, const float* __restrict__ p3,
                                                  unsigned short* o0, unsigned short* o1,
                                                  unsigned short* o2, unsigned short* o3,
                                                  int n0, int n1, int n2, int n3){
  const float* in; unsigned short* out; int n4;
  switch (blockIdx.y){
    case 0: in = p0; out = o0; n4 = n0; break;
    case 1: in = p1; out = o1; n4 = n1; break;
    case 2: in = p2; out = o2; n4 = n2; break;
    default: in = p3; out = o3; n4 = n3; break;
  }
  int i = blockIdx.x * 256 + threadIdx.x;
  if (i >= n4) return;
  f32x4 v = ((const f32x4*)in)[i];
  us4 o;
  #pragma unroll
  for (int j = 0; j < 4; ++j) o[j] = f2bf(v[j]);
  ((us4*)out)[i] = o;
}

// ---------- C-layout fp32 vals -> swizzled bf16 LDS tile -> coalesced store ----------
__device__ __forceinline__ void tile_write(unsigned short* tile, const f32x4 (&vals)[4][4],
                                           int wr, int wc, int lr, int lk){
  #pragma unroll
  for (int mt = 0; mt < 4; ++mt)
    #pragma unroll
    for (int nt = 0; nt < 4; ++nt)
      #pragma unroll
      for (int r = 0; r < 4; ++r){
        int row = wr*64 + mt*16 + lk*4 + r;
        int cb  = (wc*128 + nt*32 + lr*2) ^ ((row & 7) << 4);
        *(unsigned short*)((char*)tile + row*256 + cb) = f2bf(vals[mt][nt][r]);
      }
}
// transposed write: value for output (row=ch, col=n) -> tile[ch][n] (same swizzle family)
__device__ __forceinline__ void tile_write_T(unsigned short* tile, const f32x4 (&vals)[4][4],
                                             int wr, int wc, int lr, int lk){
  #pragma unroll
  for (int mt = 0; mt < 4; ++mt)
    #pragma unroll
    for (int nt = 0; nt < 4; ++nt)
      #pragma unroll
      for (int r = 0; r < 4; ++r){
        int n  = wr*64 + mt*16 + lk*4 + r;     // output column (time index)
        int ch = wc*64 + nt*16 + lr;           // output row (channel)
        int cb = (n*2) ^ ((ch & 7) << 4);
        *(unsigned short*)((char*)tile + ch*256 + cb) = f2bf(vals[mt][nt][r]);
      }
}
__device__ __forceinline__ void tile_flush(const unsigned short* tile, unsigned short* g,
                                           size_t row0, int col0, int ldg, int t){
  #pragma unroll
  for (int p = 0; p < 8; ++p){
    int row = p*16 + (t >> 4);
    int cb  = ((t & 15) * 16) ^ ((row & 7) << 4);
    us8 v = *(const us8*)((const char*)tile + row*256 + cb);
    *(us8*)(g + (row0 + row) * (size_t)ldg + col0 + (t & 15) * 8) = v;
  }
}

// ================= merged projection kernel (fp32 A reg-staged + cvt, bf16 W via gl_lds) =========
// r11-proven: eliminates the 131-MB activation cvt pass. 48 KB LDS: A bf16 tri-buf 3x8KB @0,
// W tri-buf 3x8KB @24576B; repack tile (32KB) aliases. Drains placed behind PCOMP.
__global__ __launch_bounds__(256, 3) void proj(const float* __restrict__ xf,
                                               const float* __restrict__ y0f,
                                               const float* __restrict__ y1f,
                                               const float* __restrict__ y2f,
                                               const unsigned short* __restrict__ wqb,
                                               const unsigned short* __restrict__ wkb,
                                               const unsigned short* __restrict__ wvb,
                                               const float* __restrict__ bq,
                                               const float* __restrict__ bk,
                                               const float* __restrict__ bv,
                                               unsigned short* __restrict__ qb,
                                               unsigned short* __restrict__ kbT,
                                               unsigned short* __restrict__ vbT,
                                               float* __restrict__ ksum){
  __shared__ unsigned short smem[24576];       // 48 KB
  const int hw = blockIdx.x;
  const int work = (hw & 7) * 256 + (hw >> 3); // XCD-chunked bijective swizzle
  int seg, ii, m0, n0;
  const float* Af;
  const unsigned short* W;
  const float* bias;
  if (work < 512){
    seg = 0; ii = 0;
    m0 = (work >> 2) << 7; n0 = (work & 3) << 7;
    Af = xf; W = wqb; bias = bq;
  } else {
    int r = work - 512;
    int g = r >> 3, s = r & 7;
    ii = g >> 6; m0 = (g & 63) << 7;
    seg = (s < 4) ? 1 : 2;
    n0 = (s & 3) << 7;
    Af = (ii == 0) ? y0f : (ii == 1 ? y1f : y2f);
    W = (seg == 1 ? wkb : wvb) + (size_t)ii*C_*C_;
    bias = (seg == 1 ? bk : bv) + (size_t)ii*C_;
  }
  const int t = threadIdx.x;
  const int w = t >> 6, l = t & 63;
  const int wr = w >> 1, wc = w & 1;
  const int lr = l & 15, lk = l >> 4;
  const int row0 = t >> 2,          b0 = t & 3;
  const int row1 = (t + 256) >> 2,  b1 = t & 3;
  f32x4 acc[4][4] = {};
  f32x4 ar0[4], ar1[4];

#define LOADA(AR, TT) { \
    const float* ap0 = Af + (size_t)(m0+row0)*C_ + (TT)*32 + b0*8; \
    const float* ap1 = Af + (size_t)(m0+row1)*C_ + (TT)*32 + b1*8; \
    AR[0] = *(const f32x4*)ap0; AR[1] = *(const f32x4*)(ap0 + 4); \
    AR[2] = *(const f32x4*)ap1; AR[3] = *(const f32x4*)(ap1 + 4); }
#define DSWA(AR, BUF) { \
    *(us8*)&smem[(BUF)*4096 + row0*32 + swz(row0,b0)*8] = cvt8(AR[0], AR[1]); \
    *(us8*)&smem[(BUF)*4096 + row1*32 + swz(row1,b1)*8] = cvt8(AR[2], AR[3]); }
#define GLW(BUF, TT) { \
    int c=t, row=c>>2; \
    gl_lds16(W + (size_t)(n0+row)*C_ + (TT)*32 + swz(row,c&3)*8, &smem[12288+(BUF)*4096 + c*8]); \
    c=t+256; row=c>>2; \
    gl_lds16(W + (size_t)(n0+row)*C_ + (TT)*32 + swz(row,c&3)*8, &smem[12288+(BUF)*4096 + c*8]); }
#define PCOMP(S, WB) { \
    const unsigned short* sA = &smem[(S)*4096]; \
    const unsigned short* sW = &smem[12288 + (WB)*4096]; \
    us8 af[4], bfr[4]; \
    _Pragma("unroll") \
    for (int mt = 0; mt < 4; ++mt){ int R = wr*64 + mt*16 + lr; af[mt] = *(const us8*)&sA[R*32 + swz(R, lk)*8]; } \
    _Pragma("unroll") \
    for (int nt = 0; nt < 4; ++nt){ int R = wc*64 + nt*16 + lr; bfr[nt] = *(const us8*)&sW[R*32 + swz(R, lk)*8]; } \
    __builtin_amdgcn_s_setprio(1); \
    _Pragma("unroll") \
    for (int mt = 0; mt < 4; ++mt) \
      _Pragma("unroll") \
      for (int nt = 0; nt < 4; ++nt) \
        acc[mt][nt] = mfma16(af[mt], bfr[nt], acc[mt][nt]); \
    __builtin_amdgcn_s_setprio(0); }
// steady-state: enter with [A(T+1)x4, W(T+1)x2] outstanding (6)
#define PSTEP(T, ARW, ARL) { \
    WAIT_VM(2); \
    DSWA(ARW, ((T)+1)%3); \
    LOADA(ARL, (T)+2); \
    GLW(((T)+2)%3, (T)+2); \
    PCOMP((T)%3, (T)%3); \
    WAIT_LGKM(); \
    WAIT_VM(6); \
    RAW_BAR(); }

  LOADA(ar0, 0); GLW(0, 0);
  LOADA(ar1, 1); GLW(1, 1);
  WAIT_VM(8);            // A(0) regs ready
  DSWA(ar0, 0);
  WAIT_LGKM();
  WAIT_VM(6);            // W(0) drained -> visible after barrier
  RAW_BAR();
  PSTEP(0,  ar1, ar0) PSTEP(1,  ar0, ar1) PSTEP(2,  ar1, ar0) PSTEP(3,  ar0, ar1)
  PSTEP(4,  ar1, ar0) PSTEP(5,  ar0, ar1) PSTEP(6,  ar1, ar0) PSTEP(7,  ar0, ar1)
  PSTEP(8,  ar1, ar0) PSTEP(9,  ar0, ar1) PSTEP(10, ar1, ar0) PSTEP(11, ar0, ar1)
  PSTEP(12, ar1, ar0) PSTEP(13, ar0, ar1)
  { // step 14: no more loads
    WAIT_VM(2);
    DSWA(ar1, 0);        // tile 15 -> bufA 0
    PCOMP(2, 2);
    WAIT_LGKM();
    WAIT_VM(0);          // W(15) drained
    RAW_BAR();
  }
  PCOMP(0, 0);           // step 15
#undef LOADA
#undef DSWA
#undef GLW
#undef PCOMP
#undef PSTEP

  // bias
  {
    float bc[4];
    #pragma unroll
    for (int nt = 0; nt < 4; ++nt) bc[nt] = bias[n0 + wc*64 + nt*16 + lr];
    #pragma unroll
    for (int mt = 0; mt < 4; ++mt)
      #pragma unroll
      for (int nt = 0; nt < 4; ++nt)
        #pragma unroll
        for (int r = 0; r < 4; ++r) acc[mt][nt][r] += bc[nt];
  }
  if (seg <= 1){
    // in-register softmax over the wave's 64-col head group
    #pragma unroll
    for (int mt = 0; mt < 4; ++mt)
      #pragma unroll
      for (int r = 0; r < 4; ++r){
        float m = fmaxf(fmaxf(acc[mt][0][r], acc[mt][1][r]), fmaxf(acc[mt][2][r], acc[mt][3][r]));
        #pragma unroll
        for (int s = 1; s < 16; s <<= 1) m = fmaxf(m, __shfl_xor(m, s, 64));
        float sum = 0.f;
        #pragma unroll
        for (int nt = 0; nt < 4; ++nt){
          float e = __expf(acc[mt][nt][r] - m);
          acc[mt][nt][r] = e; sum += e;
        }
        #pragma unroll
        for (int s = 1; s < 16; s <<= 1) sum += __shfl_xor(sum, s, 64);
        float inv = 1.0f / sum;
        #pragma unroll
        for (int nt = 0; nt < 4; ++nt) acc[mt][nt][r] *= inv;
      }
  }
  if (seg == 1){
    // colsum -> ksum atomics
    const int b = m0 >> 11;
    #pragma unroll
    for (int nt = 0; nt < 4; ++nt){
      float cs = 0.f;
      #pragma unroll
      for (int mt = 0; mt < 4; ++mt)
        #pragma unroll
        for (int r = 0; r < 4; ++r) cs += acc[mt][nt][r];
      cs += __shfl_xor(cs, 16, 64);
      cs += __shfl_xor(cs, 32, 64);
      if (lk == 0)
        atomicAdd(&ksum[((size_t)ii*B_ + b)*C_ + n0 + wc*64 + nt*16 + lr], cs);
    }
  }
  __syncthreads();
  if (seg == 0){
    tile_write(smem, acc, wr, wc, lr, lk);
    __syncthreads();
    tile_flush(smem, qb, m0, n0, C_, t);
  } else {
    tile_write_T(smem, acc, wr, wc, lr, lk);
    __syncthreads();
    const int b = m0 >> 11;
    const int n_base = m0 & 2047;
    unsigned short* gT = (seg == 1 ? kbT : vbT);
    tile_flush(smem, gT, ((size_t)ii*B_ + b)*C_ + n0, n_base, T2_, t);
  }
}

// ======== ctx single-stage MFMA: ctxTb[i][bh][e*64+d] = bf16( sum_n k[n,d] v[n,e] ) ========
// grid (32 bh, 3 i) x 256 thr; full K=2048 per block (L2/L3-resident operands, ~512 KB/block).
__global__ __launch_bounds__(256) void ctx_mfma(const unsigned short* __restrict__ kbT,
                                                const unsigned short* __restrict__ vbT,
                                                unsigned short* __restrict__ ctxTb){
  const int bh = blockIdx.x, i = blockIdx.y;
  const int b = bh >> 3, h = bh & 7;
  const size_t rowbase = ((size_t)i*B_ + b)*C_ + h*64;
  const unsigned short* kT = kbT + rowbase*T2_;
  const unsigned short* vT = vbT + rowbase*T2_;
  const int t = threadIdx.x;
  const int w = t >> 6, l = t & 63;
  const int qr = w >> 1, qc = w & 1;     // 32x32 quadrant per wave
  const int lr = l & 15, lk = l >> 4;
  f32x4 acc[2][2] = {};
  #pragma unroll 4
  for (int it = 0; it < 64; ++it){
    const int k0 = it*32 + lk*8;
    us8 a0 = *(const us8*)(kT + (size_t)(qr*32 +      lr)*T2_ + k0);
    us8 a1 = *(const us8*)(kT + (size_t)(qr*32 + 16 + lr)*T2_ + k0);
    us8 b0 = *(const us8*)(vT + (size_t)(qc*32 +      lr)*T2_ + k0);
    us8 b1 = *(const us8*)(vT + (size_t)(qc*32 + 16 + lr)*T2_ + k0);
    acc[0][0] = mfma16(a0, b0, acc[0][0]);
    acc[0][1] = mfma16(a0, b1, acc[0][1]);
    acc[1][0] = mfma16(a1, b0, acc[1][0]);
    acc[1][1] = mfma16(a1, b1, acc[1][1]);
  }
  unsigned short* dst = ctxTb + ((size_t)i*32 + bh)*4096;
  #pragma unroll
  for (int fa = 0; fa < 2; ++fa)
    #pragma unroll
    for (int fb = 0; fb < 2; ++fb){
      int d0 = qr*32 + fa*16 + lk*4;
      int e  = qc*32 + fb*16 + lr;
      us4 o;
      #pragma unroll
      for (int j = 0; j < 4; ++j) o[j] = f2bf(acc[fa][fb][j]);
      *(us4*)(dst + e*64 + d0) = o;
    }
}

// ================= combine: omid = q + sum_i (q @ ctx_i) * Dinv_i =================
__global__ __launch_bounds__(256) void combine(const unsigned short* __restrict__ qb,
                                               const unsigned short* __restrict__ ctxTb,
                                               const float* __restrict__ ksum,
                                               unsigned short* __restrict__ omid){
  __shared__ unsigned short tile[128*128];
  const int hw = blockIdx.x;
  const int work = (hw & 7) * 64 + (hw >> 3);
  const int m0 = (work & 127) << 7, n0 = (work >> 7) << 7;
  const int t = threadIdx.x;
  const int w = t >> 6, l = t & 63;
  const int wr = w >> 1, wc = w & 1;
  const int lr = l & 15, lk = l >> 4;
  const int b = m0 >> 12;
  const int bh = b*8 + (n0 >> 6) + wc;
  #pragma unroll
  for (int p = 0; p < 8; ++p){
    int idx = p*256 + t;
    int row = idx >> 4, ch = idx & 15;
    gl_lds16(qb + (size_t)(m0+row)*C_ + n0 + (ch ^ (row & 7))*8, &tile[idx*8]);
  }
  WAIT_VM(0);
  __syncthreads();
  us8 afr[4][2];
  #pragma unroll
  for (int mt = 0; mt < 4; ++mt)
    #pragma unroll
    for (int kk = 0; kk < 2; ++kk){
      int row = wr*64 + mt*16 + lr;
      int ch = wc*8 + kk*4 + lk;
      afr[mt][kk] = *(const us8*)((const char*)tile + row*256 + ((ch ^ (row & 7)) << 4));
    }
  f32x4 acc[4][4];
  #pragma unroll
  for (int mt = 0; mt < 4; ++mt)
    #pragma unroll
    for (int nt = 0; nt < 4; ++nt)
      #pragma unroll
      for (int r = 0; r < 4; ++r){
        int row = wr*64 + mt*16 + lk*4 + r;
        int cbyte = wc*128 + nt*32 + lr*2;
        int ch = cbyte >> 4;
        unsigned short v = *(const unsigned short*)((const char*)tile + row*256 +
                            ((ch ^ (row & 7)) << 4) + (cbyte & 15));
        acc[mt][nt][r] = bf2f(v);
      }
  us8 bden[2];
  #pragma unroll
  for (int kk = 0; kk < 2; ++kk){
    us8 tmp = {};
    if (lr < 3){
      const float* kp = ksum + ((size_t)lr*B_ + b)*C_ + n0 + wc*64 + kk*32 + lk*8;
      f32x4 c0 = *(const f32x4*)kp;
      f32x4 c1 = *(const f32x4*)(kp + 4);
      #pragma unroll
      for (int j = 0; j < 4; ++j){ tmp[j] = f2bf(c0[j]); tmp[4+j] = f2bf(c1[j]); }
    }
    bden[kk] = tmp;
  }
  f32x4 den[4] = {};
  #pragma unroll
  for (int mt = 0; mt < 4; ++mt)
    #pragma unroll
    for (int kk = 0; kk < 2; ++kk)
      den[mt] = mfma16(afr[mt][kk], bden[kk], den[mt]);
  #pragma unroll 1
  for (int i = 0; i < 3; ++i){
    f32x4 dinv[4];
    #pragma unroll
    for (int mt = 0; mt < 4; ++mt)
      #pragma unroll
      for (int r = 0; r < 4; ++r)
        dinv[mt][r] = 1.0f / (__shfl(den[mt][r], (l & 48) | i, 64) + 1e-8f);
    #pragma unroll
    for (int nt = 0; nt < 4; ++nt){
      us8 bfr[2];
      #pragma unroll
      for (int kk = 0; kk < 2; ++kk)
        bfr[kk] = *(const us8*)(ctxTb + ((size_t)(i*32 + bh))*4096 + (nt*16 + lr)*64 + kk*32 + lk*8);
      f32x4 p[4] = {};
      #pragma unroll
      for (int mt = 0; mt < 4; ++mt)
        #pragma unroll
        for (int kk = 0; kk < 2; ++kk)
          p[mt] = mfma16(afr[mt][kk], bfr[kk], p[mt]);
      #pragma unroll
      for (int mt = 0; mt < 4; ++mt)
        #pragma unroll
        for (int r = 0; r < 4; ++r)
          acc[mt][nt][r] += p[mt][r] * dinv[mt][r];
    }
  }
  __syncthreads();
  tile_write(tile, acc, wr, wc, lr, lk);
  __syncthreads();
  tile_flush(tile, omid, m0, n0, C_, t);
}

// ---------------- O-proj GEMM (3-buf, RACE-FREE depth-2 counted-vmcnt) ----------------
__global__ __launch_bounds__(256, 3) void gemm_bt(const unsigned short* __restrict__ A,
                                                  const unsigned short* __restrict__ Bw,
                                                  const float* __restrict__ bias,
                                                  float* __restrict__ out){
  __shared__ unsigned short smem[3*2*4096];
  const int hw = blockIdx.x;
  const int work = (hw & 7) * 64 + (hw >> 3);
  const int m0 = ((work >> 2) & 127) << 7, n0 = (work & 3) << 7;
  const int t = threadIdx.x;
  const int w = t >> 6, l = t & 63;
  const int wr = w >> 1, wc = w & 1;
  const int lr = l & 15, lk = l >> 4;
  f32x4 acc[4][4] = {};

#define GSTAGE(BB, TT) { \
    int c = t, row = c >> 2; \
    gl_lds16(A  + (size_t)(m0+row)*C_ + (TT)*32 + swz(row, c & 3)*8, &smem[(BB)*8192 + c*8]); \
    gl_lds16(Bw + (size_t)(n0+row)*C_ + (TT)*32 + swz(row, c & 3)*8, &smem[(BB)*8192 + 4096 + c*8]); \
    c = t + 256; row = c >> 2; \
    gl_lds16(A  + (size_t)(m0+row)*C_ + (TT)*32 + swz(row, c & 3)*8, &smem[(BB)*8192 + c*8]); \
    gl_lds16(Bw + (size_t)(n0+row)*C_ + (TT)*32 + swz(row, c & 3)*8, &smem[(BB)*8192 + 4096 + c*8]); }
#define GCOMP(BB) { \
    const unsigned short* sA = &smem[(BB)*8192]; \
    const unsigned short* sB = &smem[(BB)*8192 + 4096]; \
    us8 af[4], bfr[4]; \
    _Pragma("unroll") \
    for (int mt = 0; mt < 4; ++mt){ int R = wr*64 + mt*16 + lr; af[mt] = *(const us8*)&sA[R*32 + swz(R, lk)*8]; } \
    _Pragma("unroll") \
    for (int nt = 0; nt < 4; ++nt){ int R = wc*64 + nt*16 + lr; bfr[nt] = *(const us8*)&sB[R*32 + swz(R, lk)*8]; } \
    __builtin_amdgcn_s_setprio(1); \
    _Pragma("unroll") \
    for (int mt = 0; mt < 4; ++mt) \
      _Pragma("unroll") \
      for (int nt = 0; nt < 4; ++nt) \
        acc[mt][nt] = mfma16(af[mt], bfr[nt], acc[mt][nt]); \
    __builtin_amdgcn_s_setprio(0); }
#define GSTEP(T, N) { \
    WAIT_VM(N); \
    RAW_BAR(); \
    if ((T) + 2 < 16) GSTAGE(((T)+2)%3, (T)+2); \
    GCOMP((T)%3); }

  GSTAGE(0, 0); GSTAGE(1, 1);
  GSTEP(0, 4)  GSTEP(1, 4)  GSTEP(2, 4)  GSTEP(3, 4)
  GSTEP(4, 4)  GSTEP(5, 4)  GSTEP(6, 4)  GSTEP(7, 4)
  GSTEP(8, 4)  GSTEP(9, 4)  GSTEP(10, 4) GSTEP(11, 4)
  GSTEP(12, 4) GSTEP(13, 4) GSTEP(14, 4) GSTEP(15, 0)
#undef GSTAGE
#undef GCOMP
#undef GSTEP

  #pragma unroll
  for (int mt = 0; mt < 4; ++mt)
    #pragma unroll
    for (int nt = 0; nt < 4; ++nt)
      #pragma unroll
      for (int r = 0; r < 4; ++r){
        int row = m0 + wr*64 + mt*16 + lk*4 + r;
        int col = n0 + wc*64 + nt*16 + lr;
        out[(size_t)row*C_ + col] = acc[mt][nt][r] + bias[col];
      }
}

extern "C" void kernel_launch(void* const* d_in, const int* in_sizes, int n_in,
                              void* d_out, int out_size, void* d_ws, size_t ws_size,
                              hipStream_t stream){
  const float* x  = (const float*)d_in[0];
  const float* y0 = (const float*)d_in[1];
  const float* y1 = (const float*)d_in[2];
  const float* y2 = (const float*)d_in[3];
  const float* Wq = (const float*)d_in[4];
  const float* bq = (const float*)d_in[5];
  const float* Wk = (const float*)d_in[6];
  const float* bk = (const float*)d_in[7];
  const float* Wv = (const float*)d_in[8];
  const float* bv = (const float*)d_in[9];
  const float* Wo = (const float*)d_in[10];
  const float* bo = (const float*)d_in[11];

  char* ws = (char*)d_ws;
  size_t off = 0;
  auto alloc = [&](size_t bytes)->char*{
    char* p = ws + off; off += (bytes + 1023) & ~((size_t)1023); return p;
  };
  unsigned short* wqb   = (unsigned short*)alloc((size_t)C_*C_*2);
  unsigned short* wkb   = (unsigned short*)alloc((size_t)3*C_*C_*2);
  unsigned short* wvb   = (unsigned short*)alloc((size_t)3*C_*C_*2);
  unsigned short* wob   = (unsigned short*)alloc((size_t)C_*C_*2);
  unsigned short* qb    = (unsigned short*)alloc((size_t)M1_*C_*2);
  unsigned short* kbT   = (unsigned short*)alloc((size_t)3*B_*C_*T2_*2);
  unsigned short* vbT   = (unsigned short*)alloc((size_t)3*B_*C_*T2_*2);
  float*          ksum  = (float*)alloc((size_t)3*B_*C_*4);
  unsigned short* ctxTb = (unsigned short*)alloc((size_t)3*32*4096*2);
  unsigned short* omid  = (unsigned short*)alloc((size_t)M1_*C_*2);

  (void)hipMemsetAsync(ksum, 0, (size_t)3*B_*C_*4, stream);

  // weights-only convert (~1.5 MB)
  cvt_bf16_4<<<dim3(3*C_*C_/4/256, 4), 256, 0, stream>>>(
      Wq, Wk, Wv, Wo, wqb, wkb, wvb, wob,
      C_*C_/4, 3*C_*C_/4, 3*C_*C_/4, C_*C_/4);

  proj<<<2048, 256, 0, stream>>>(x, y0, y1, y2, wqb, wkb, wvb, bq, bk, bv, qb, kbT, vbT, ksum);
  ctx_mfma<<<dim3(32, 3), 256, 0, stream>>>(kbT, vbT, ctxTb);
  combine<<<512, 256, 0, stream>>>(qb, ctxTb, ksum, omid);
  gemm_bt<<<512, 256, 0, stream>>>(omid, wob, bo, (float*)d_out);
}

// Round 17
// 127.969 us; speedup vs baseline: 1.0843x; 1.0843x over previous
//
#include <hip/hip_runtime.h>
#include <stdint.h>

#define B_ 4
#define T1_ 4096
#define T2_ 2048
#define C_ 512
#define H_ 8
#define D_ 64
#define M1_ (B_*T1_)   // 16384
#define M2_ (B_*T2_)   // 8192

using f32x4 = __attribute__((ext_vector_type(4))) float;
using bf16x8 = __attribute__((ext_vector_type(8))) __bf16;
using us8 = __attribute__((ext_vector_type(8))) unsigned short;
using us4 = __attribute__((ext_vector_type(4))) unsigned short;

__device__ __forceinline__ unsigned short f2bf(float f){
  unsigned int u = __builtin_bit_cast(unsigned int, f);
  unsigned int r = (u + 0x7fffu + ((u >> 16) & 1u)) >> 16;
  return (unsigned short)r;
}
__device__ __forceinline__ float bf2f(unsigned short u){
  return __builtin_bit_cast(float, ((unsigned int)u) << 16);
}
__device__ __forceinline__ f32x4 mfma16(us8 a, us8 b, f32x4 c){
  return __builtin_amdgcn_mfma_f32_16x16x32_bf16(
      __builtin_bit_cast(bf16x8, a), __builtin_bit_cast(bf16x8, b), c, 0, 0, 0);
}
// hot-path cvt: compiler emits packed v_cvt (m240: prefer cast over hand-asm)
__device__ __forceinline__ us8 cvt8(f32x4 a, f32x4 b){
  us8 v;
  #pragma unroll
  for (int j = 0; j < 4; ++j){
    v[j]   = __builtin_bit_cast(unsigned short, (__bf16)a[j]);
    v[4+j] = __builtin_bit_cast(unsigned short, (__bf16)b[j]);
  }
  return v;
}

typedef const __attribute__((address_space(1))) unsigned int gu32;
typedef __attribute__((address_space(3))) unsigned int lu32;
__device__ __forceinline__ void gl_lds16(const void* g, void* l){
  __builtin_amdgcn_global_load_lds((gu32*)g, (lu32*)l, 16, 0, 0);
}

#define WAIT_VM(N) asm volatile("s_waitcnt vmcnt(" #N ")" ::: "memory")
#define WAIT_LGKM() asm volatile("s_waitcnt lgkmcnt(0)" ::: "memory")
#define RAW_BAR()  { __builtin_amdgcn_s_barrier(); __builtin_amdgcn_sched_barrier(0); }

// chunk swizzle for the K-loop staging (involution, rule 21)
__device__ __forceinline__ int swz(int row, int blk){ return blk ^ ((row >> 1) & 3); }

// ---------------- fp32 -> bf16 convert (weights only) ----------------
__global__ __launch_bounds__(256) void cvt_bf16_4(const float* __restrict__ p0, const float* __restrict__ p1,
                                                  const float* __restrict__ p2, const float* __restrict__ p3,
                                                  unsigned short* o0, unsigned short* o1,
                                                  unsigned short* o2, unsigned short* o3,
                                                  int n0, int n1, int n2, int n3){
  const float* in; unsigned short* out; int n4;
  switch (blockIdx.y){
    case 0: in = p0; out = o0; n4 = n0; break;
    case 1: in = p1; out = o1; n4 = n1; break;
    case 2: in = p2; out = o2; n4 = n2; break;
    default: in = p3; out = o3; n4 = n3; break;
  }
  int i = blockIdx.x * 256 + threadIdx.x;
  if (i >= n4) return;
  f32x4 v = ((const f32x4*)in)[i];
  us4 o;
  #pragma unroll
  for (int j = 0; j < 4; ++j) o[j] = f2bf(v[j]);
  ((us4*)out)[i] = o;
}

// ---------- C-layout fp32 vals -> swizzled bf16 LDS tile -> coalesced store ----------
__device__ __forceinline__ void tile_write(unsigned short* tile, const f32x4 (&vals)[4][4],
                                           int wr, int wc, int lr, int lk){
  #pragma unroll
  for (int mt = 0; mt < 4; ++mt)
    #pragma unroll
    for (int nt = 0; nt < 4; ++nt)
      #pragma unroll
      for (int r = 0; r < 4; ++r){
        int row = wr*64 + mt*16 + lk*4 + r;
        int cb  = (wc*128 + nt*32 + lr*2) ^ ((row & 7) << 4);
        *(unsigned short*)((char*)tile + row*256 + cb) = f2bf(vals[mt][nt][r]);
      }
}
// transposed write: value for output (row=ch, col=n) -> tile[ch][n] (same swizzle family)
__device__ __forceinline__ void tile_write_T(unsigned short* tile, const f32x4 (&vals)[4][4],
                                             int wr, int wc, int lr, int lk){
  #pragma unroll
  for (int mt = 0; mt < 4; ++mt)
    #pragma unroll
    for (int nt = 0; nt < 4; ++nt)
      #pragma unroll
      for (int r = 0; r < 4; ++r){
        int n  = wr*64 + mt*16 + lk*4 + r;     // output column (time index)
        int ch = wc*64 + nt*16 + lr;           // output row (channel)
        int cb = (n*2) ^ ((ch & 7) << 4);
        *(unsigned short*)((char*)tile + ch*256 + cb) = f2bf(vals[mt][nt][r]);
      }
}
__device__ __forceinline__ void tile_flush(const unsigned short* tile, unsigned short* g,
                                           size_t row0, int col0, int ldg, int t){
  #pragma unroll
  for (int p = 0; p < 8; ++p){
    int row = p*16 + (t >> 4);
    int cb  = ((t & 15) * 16) ^ ((row & 7) << 4);
    us8 v = *(const us8*)((const char*)tile + row*256 + cb);
    *(us8*)(g + (row0 + row) * (size_t)ldg + col0 + (t & 15) * 8) = v;
  }
}

// ================= merged projection kernel (fp32 A reg-staged + cvt, bf16 W via gl_lds) =========
// r11-proven: eliminates the 131-MB activation cvt pass. 48 KB LDS: A bf16 tri-buf 3x8KB @0,
// W tri-buf 3x8KB @24576B; repack tile (32KB) aliases. Drains placed behind PCOMP.
__global__ __launch_bounds__(256, 3) void proj(const float* __restrict__ xf,
                                               const float* __restrict__ y0f,
                                               const float* __restrict__ y1f,
                                               const float* __restrict__ y2f,
                                               const unsigned short* __restrict__ wqb,
                                               const unsigned short* __restrict__ wkb,
                                               const unsigned short* __restrict__ wvb,
                                               const float* __restrict__ bq,
                                               const float* __restrict__ bk,
                                               const float* __restrict__ bv,
                                               unsigned short* __restrict__ qb,
                                               unsigned short* __restrict__ kbT,
                                               unsigned short* __restrict__ vbT,
                                               float* __restrict__ ksum){
  __shared__ unsigned short smem[24576];       // 48 KB
  const int hw = blockIdx.x;
  const int work = (hw & 7) * 256 + (hw >> 3); // XCD-chunked bijective swizzle
  int seg, ii, m0, n0;
  const float* Af;
  const unsigned short* W;
  const float* bias;
  if (work < 512){
    seg = 0; ii = 0;
    m0 = (work >> 2) << 7; n0 = (work & 3) << 7;
    Af = xf; W = wqb; bias = bq;
  } else {
    int r = work - 512;
    int g = r >> 3, s = r & 7;
    ii = g >> 6; m0 = (g & 63) << 7;
    seg = (s < 4) ? 1 : 2;
    n0 = (s & 3) << 7;
    Af = (ii == 0) ? y0f : (ii == 1 ? y1f : y2f);
    W = (seg == 1 ? wkb : wvb) + (size_t)ii*C_*C_;
    bias = (seg == 1 ? bk : bv) + (size_t)ii*C_;
  }
  const int t = threadIdx.x;
  const int w = t >> 6, l = t & 63;
  const int wr = w >> 1, wc = w & 1;
  const int lr = l & 15, lk = l >> 4;
  const int row0 = t >> 2,          b0 = t & 3;
  const int row1 = (t + 256) >> 2,  b1 = t & 3;
  f32x4 acc[4][4] = {};
  f32x4 ar0[4], ar1[4];

#define LOADA(AR, TT) { \
    const float* ap0 = Af + (size_t)(m0+row0)*C_ + (TT)*32 + b0*8; \
    const float* ap1 = Af + (size_t)(m0+row1)*C_ + (TT)*32 + b1*8; \
    AR[0] = *(const f32x4*)ap0; AR[1] = *(const f32x4*)(ap0 + 4); \
    AR[2] = *(const f32x4*)ap1; AR[3] = *(const f32x4*)(ap1 + 4); }
#define DSWA(AR, BUF) { \
    *(us8*)&smem[(BUF)*4096 + row0*32 + swz(row0,b0)*8] = cvt8(AR[0], AR[1]); \
    *(us8*)&smem[(BUF)*4096 + row1*32 + swz(row1,b1)*8] = cvt8(AR[2], AR[3]); }
#define GLW(BUF, TT) { \
    int c=t, row=c>>2; \
    gl_lds16(W + (size_t)(n0+row)*C_ + (TT)*32 + swz(row,c&3)*8, &smem[12288+(BUF)*4096 + c*8]); \
    c=t+256; row=c>>2; \
    gl_lds16(W + (size_t)(n0+row)*C_ + (TT)*32 + swz(row,c&3)*8, &smem[12288+(BUF)*4096 + c*8]); }
#define PCOMP(S, WB) { \
    const unsigned short* sA = &smem[(S)*4096]; \
    const unsigned short* sW = &smem[12288 + (WB)*4096]; \
    us8 af[4], bfr[4]; \
    _Pragma("unroll") \
    for (int mt = 0; mt < 4; ++mt){ int R = wr*64 + mt*16 + lr; af[mt] = *(const us8*)&sA[R*32 + swz(R, lk)*8]; } \
    _Pragma("unroll") \
    for (int nt = 0; nt < 4; ++nt){ int R = wc*64 + nt*16 + lr; bfr[nt] = *(const us8*)&sW[R*32 + swz(R, lk)*8]; } \
    __builtin_amdgcn_s_setprio(1); \
    _Pragma("unroll") \
    for (int mt = 0; mt < 4; ++mt) \
      _Pragma("unroll") \
      for (int nt = 0; nt < 4; ++nt) \
        acc[mt][nt] = mfma16(af[mt], bfr[nt], acc[mt][nt]); \
    __builtin_amdgcn_s_setprio(0); }
// steady-state: enter with [A(T+1)x4, W(T+1)x2] outstanding (6)
#define PSTEP(T, ARW, ARL) { \
    WAIT_VM(2); \
    DSWA(ARW, ((T)+1)%3); \
    LOADA(ARL, (T)+2); \
    GLW(((T)+2)%3, (T)+2); \
    PCOMP((T)%3, (T)%3); \
    WAIT_LGKM(); \
    WAIT_VM(6); \
    RAW_BAR(); }

  LOADA(ar0, 0); GLW(0, 0);
  LOADA(ar1, 1); GLW(1, 1);
  WAIT_VM(8);            // A(0) regs ready
  DSWA(ar0, 0);
  WAIT_LGKM();
  WAIT_VM(6);            // W(0) drained -> visible after barrier
  RAW_BAR();
  PSTEP(0,  ar1, ar0) PSTEP(1,  ar0, ar1) PSTEP(2,  ar1, ar0) PSTEP(3,  ar0, ar1)
  PSTEP(4,  ar1, ar0) PSTEP(5,  ar0, ar1) PSTEP(6,  ar1, ar0) PSTEP(7,  ar0, ar1)
  PSTEP(8,  ar1, ar0) PSTEP(9,  ar0, ar1) PSTEP(10, ar1, ar0) PSTEP(11, ar0, ar1)
  PSTEP(12, ar1, ar0) PSTEP(13, ar0, ar1)
  { // step 14: no more loads
    WAIT_VM(2);
    DSWA(ar1, 0);        // tile 15 -> bufA 0
    PCOMP(2, 2);
    WAIT_LGKM();
    WAIT_VM(0);          // W(15) drained
    RAW_BAR();
  }
  PCOMP(0, 0);           // step 15
#undef LOADA
#undef DSWA
#undef GLW
#undef PCOMP
#undef PSTEP

  // bias
  {
    float bc[4];
    #pragma unroll
    for (int nt = 0; nt < 4; ++nt) bc[nt] = bias[n0 + wc*64 + nt*16 + lr];
    #pragma unroll
    for (int mt = 0; mt < 4; ++mt)
      #pragma unroll
      for (int nt = 0; nt < 4; ++nt)
        #pragma unroll
        for (int r = 0; r < 4; ++r) acc[mt][nt][r] += bc[nt];
  }
  if (seg <= 1){
    // in-register softmax over the wave's 64-col head group
    #pragma unroll
    for (int mt = 0; mt < 4; ++mt)
      #pragma unroll
      for (int r = 0; r < 4; ++r){
        float m = fmaxf(fmaxf(acc[mt][0][r], acc[mt][1][r]), fmaxf(acc[mt][2][r], acc[mt][3][r]));
        #pragma unroll
        for (int s = 1; s < 16; s <<= 1) m = fmaxf(m, __shfl_xor(m, s, 64));
        float sum = 0.f;
        #pragma unroll
        for (int nt = 0; nt < 4; ++nt){
          float e = __expf(acc[mt][nt][r] - m);
          acc[mt][nt][r] = e; sum += e;
        }
        #pragma unroll
        for (int s = 1; s < 16; s <<= 1) sum += __shfl_xor(sum, s, 64);
        float inv = 1.0f / sum;
        #pragma unroll
        for (int nt = 0; nt < 4; ++nt) acc[mt][nt][r] *= inv;
      }
  }
  if (seg == 1){
    // colsum -> ksum atomics
    const int b = m0 >> 11;
    #pragma unroll
    for (int nt = 0; nt < 4; ++nt){
      float cs = 0.f;
      #pragma unroll
      for (int mt = 0; mt < 4; ++mt)
        #pragma unroll
        for (int r = 0; r < 4; ++r) cs += acc[mt][nt][r];
      cs += __shfl_xor(cs, 16, 64);
      cs += __shfl_xor(cs, 32, 64);
      if (lk == 0)
        atomicAdd(&ksum[((size_t)ii*B_ + b)*C_ + n0 + wc*64 + nt*16 + lr], cs);
    }
  }
  __syncthreads();
  if (seg == 0){
    tile_write(smem, acc, wr, wc, lr, lk);
    __syncthreads();
    tile_flush(smem, qb, m0, n0, C_, t);
  } else {
    tile_write_T(smem, acc, wr, wc, lr, lk);
    __syncthreads();
    const int b = m0 >> 11;
    const int n_base = m0 & 2047;
    unsigned short* gT = (seg == 1 ? kbT : vbT);
    tile_flush(smem, gT, ((size_t)ii*B_ + b)*C_ + n0, n_base, T2_, t);
  }
}

// ================= ctx via MFMA (two-stage split-K, proven): part -> reduce =================
__global__ __launch_bounds__(256) void ctx_mfma(const unsigned short* __restrict__ kbT,
                                                const unsigned short* __restrict__ vbT,
                                                float* __restrict__ part){
  const int bh = blockIdx.x, kc = blockIdx.y, i = blockIdx.z;
  const int b = bh >> 3, h = bh & 7;
  const size_t rowbase = ((size_t)i*B_ + b)*C_ + h*64;
  const unsigned short* kT = kbT + rowbase*T2_;
  const unsigned short* vT = vbT + rowbase*T2_;
  const int t = threadIdx.x;
  const int w = t >> 6, l = t & 63;
  const int qr = w >> 1, qc = w & 1;     // 32x32 quadrant per wave
  const int lr = l & 15, lk = l >> 4;
  const int n00 = kc * 256;
  f32x4 acc[2][2] = {};
  #pragma unroll
  for (int it = 0; it < 8; ++it){
    const int k0 = n00 + it*32 + lk*8;
    us8 a0 = *(const us8*)(kT + (size_t)(qr*32 +      lr)*T2_ + k0);
    us8 a1 = *(const us8*)(kT + (size_t)(qr*32 + 16 + lr)*T2_ + k0);
    us8 b0 = *(const us8*)(vT + (size_t)(qc*32 +      lr)*T2_ + k0);
    us8 b1 = *(const us8*)(vT + (size_t)(qc*32 + 16 + lr)*T2_ + k0);
    acc[0][0] = mfma16(a0, b0, acc[0][0]);
    acc[0][1] = mfma16(a0, b1, acc[0][1]);
    acc[1][0] = mfma16(a1, b0, acc[1][0]);
    acc[1][1] = mfma16(a1, b1, acc[1][1]);
  }
  float* dst = part + (((size_t)i*8 + kc)*32 + bh)*4096;
  #pragma unroll
  for (int fa = 0; fa < 2; ++fa)
    #pragma unroll
    for (int fb = 0; fb < 2; ++fb){
      int d0 = qr*32 + fa*16 + lk*4;
      int e  = qc*32 + fb*16 + lr;
      *(f32x4*)(dst + e*64 + d0) = acc[fa][fb];
    }
}

__global__ __launch_bounds__(256) void ctx_reduce(const float* __restrict__ part,
                                                  unsigned short* __restrict__ ctxTb){
  const int bh = blockIdx.x, i = blockIdx.y, t = threadIdx.x;
  for (int idx = t; idx < 4096; idx += 256){
    float s = 0.f;
    #pragma unroll
    for (int kc = 0; kc < 8; ++kc)
      s += part[(((size_t)i*8 + kc)*32 + bh)*4096 + idx];
    ctxTb[((size_t)i*32 + bh)*4096 + idx] = f2bf(s);
  }
}

// ================= combine: omid = q + sum_i (q @ ctx_i) * Dinv_i =================
__global__ __launch_bounds__(256) void combine(const unsigned short* __restrict__ qb,
                                               const unsigned short* __restrict__ ctxTb,
                                               const float* __restrict__ ksum,
                                               unsigned short* __restrict__ omid){
  __shared__ unsigned short tile[128*128];
  const int hw = blockIdx.x;
  const int work = (hw & 7) * 64 + (hw >> 3);
  const int m0 = (work & 127) << 7, n0 = (work >> 7) << 7;
  const int t = threadIdx.x;
  const int w = t >> 6, l = t & 63;
  const int wr = w >> 1, wc = w & 1;
  const int lr = l & 15, lk = l >> 4;
  const int b = m0 >> 12;
  const int bh = b*8 + (n0 >> 6) + wc;
  #pragma unroll
  for (int p = 0; p < 8; ++p){
    int idx = p*256 + t;
    int row = idx >> 4, ch = idx & 15;
    gl_lds16(qb + (size_t)(m0+row)*C_ + n0 + (ch ^ (row & 7))*8, &tile[idx*8]);
  }
  WAIT_VM(0);
  __syncthreads();
  us8 afr[4][2];
  #pragma unroll
  for (int mt = 0; mt < 4; ++mt)
    #pragma unroll
    for (int kk = 0; kk < 2; ++kk){
      int row = wr*64 + mt*16 + lr;
      int ch = wc*8 + kk*4 + lk;
      afr[mt][kk] = *(const us8*)((const char*)tile + row*256 + ((ch ^ (row & 7)) << 4));
    }
  f32x4 acc[4][4];
  #pragma unroll
  for (int mt = 0; mt < 4; ++mt)
    #pragma unroll
    for (int nt = 0; nt < 4; ++nt)
      #pragma unroll
      for (int r = 0; r < 4; ++r){
        int row = wr*64 + mt*16 + lk*4 + r;
        int cbyte = wc*128 + nt*32 + lr*2;
        int ch = cbyte >> 4;
        unsigned short v = *(const unsigned short*)((const char*)tile + row*256 +
                            ((ch ^ (row & 7)) << 4) + (cbyte & 15));
        acc[mt][nt][r] = bf2f(v);
      }
  us8 bden[2];
  #pragma unroll
  for (int kk = 0; kk < 2; ++kk){
    us8 tmp = {};
    if (lr < 3){
      const float* kp = ksum + ((size_t)lr*B_ + b)*C_ + n0 + wc*64 + kk*32 + lk*8;
      f32x4 c0 = *(const f32x4*)kp;
      f32x4 c1 = *(const f32x4*)(kp + 4);
      #pragma unroll
      for (int j = 0; j < 4; ++j){ tmp[j] = f2bf(c0[j]); tmp[4+j] = f2bf(c1[j]); }
    }
    bden[kk] = tmp;
  }
  f32x4 den[4] = {};
  #pragma unroll
  for (int mt = 0; mt < 4; ++mt)
    #pragma unroll
    for (int kk = 0; kk < 2; ++kk)
      den[mt] = mfma16(afr[mt][kk], bden[kk], den[mt]);
  #pragma unroll 1
  for (int i = 0; i < 3; ++i){
    f32x4 dinv[4];
    #pragma unroll
    for (int mt = 0; mt < 4; ++mt)
      #pragma unroll
      for (int r = 0; r < 4; ++r)
        dinv[mt][r] = 1.0f / (__shfl(den[mt][r], (l & 48) | i, 64) + 1e-8f);
    #pragma unroll
    for (int nt = 0; nt < 4; ++nt){
      us8 bfr[2];
      #pragma unroll
      for (int kk = 0; kk < 2; ++kk)
        bfr[kk] = *(const us8*)(ctxTb + ((size_t)(i*32 + bh))*4096 + (nt*16 + lr)*64 + kk*32 + lk*8);
      f32x4 p[4] = {};
      #pragma unroll
      for (int mt = 0; mt < 4; ++mt)
        #pragma unroll
        for (int kk = 0; kk < 2; ++kk)
          p[mt] = mfma16(afr[mt][kk], bfr[kk], p[mt]);
      #pragma unroll
      for (int mt = 0; mt < 4; ++mt)
        #pragma unroll
        for (int r = 0; r < 4; ++r)
          acc[mt][nt][r] += p[mt][r] * dinv[mt][r];
    }
  }
  __syncthreads();
  tile_write(tile, acc, wr, wc, lr, lk);
  __syncthreads();
  tile_flush(tile, omid, m0, n0, C_, t);
}

// ---------------- O-proj GEMM (3-buf, RACE-FREE depth-2 counted-vmcnt) ----------------
__global__ __launch_bounds__(256, 3) void gemm_bt(const unsigned short* __restrict__ A,
                                                  const unsigned short* __restrict__ Bw,
                                                  const float* __restrict__ bias,
                                                  float* __restrict__ out){
  __shared__ unsigned short smem[3*2*4096];
  const int hw = blockIdx.x;
  const int work = (hw & 7) * 64 + (hw >> 3);
  const int m0 = ((work >> 2) & 127) << 7, n0 = (work & 3) << 7;
  const int t = threadIdx.x;
  const int w = t >> 6, l = t & 63;
  const int wr = w >> 1, wc = w & 1;
  const int lr = l & 15, lk = l >> 4;
  f32x4 acc[4][4] = {};

#define GSTAGE(BB, TT) { \
    int c = t, row = c >> 2; \
    gl_lds16(A  + (size_t)(m0+row)*C_ + (TT)*32 + swz(row, c & 3)*8, &smem[(BB)*8192 + c*8]); \
    gl_lds16(Bw + (size_t)(n0+row)*C_ + (TT)*32 + swz(row, c & 3)*8, &smem[(BB)*8192 + 4096 + c*8]); \
    c = t + 256; row = c >> 2; \
    gl_lds16(A  + (size_t)(m0+row)*C_ + (TT)*32 + swz(row, c & 3)*8, &smem[(BB)*8192 + c*8]); \
    gl_lds16(Bw + (size_t)(n0+row)*C_ + (TT)*32 + swz(row, c & 3)*8, &smem[(BB)*8192 + 4096 + c*8]); }
#define GCOMP(BB) { \
    const unsigned short* sA = &smem[(BB)*8192]; \
    const unsigned short* sB = &smem[(BB)*8192 + 4096]; \
    us8 af[4], bfr[4]; \
    _Pragma("unroll") \
    for (int mt = 0; mt < 4; ++mt){ int R = wr*64 + mt*16 + lr; af[mt] = *(const us8*)&sA[R*32 + swz(R, lk)*8]; } \
    _Pragma("unroll") \
    for (int nt = 0; nt < 4; ++nt){ int R = wc*64 + nt*16 + lr; bfr[nt] = *(const us8*)&sB[R*32 + swz(R, lk)*8]; } \
    __builtin_amdgcn_s_setprio(1); \
    _Pragma("unroll") \
    for (int mt = 0; mt < 4; ++mt) \
      _Pragma("unroll") \
      for (int nt = 0; nt < 4; ++nt) \
        acc[mt][nt] = mfma16(af[mt], bfr[nt], acc[mt][nt]); \
    __builtin_amdgcn_s_setprio(0); }
#define GSTEP(T, N) { \
    WAIT_VM(N); \
    RAW_BAR(); \
    if ((T) + 2 < 16) GSTAGE(((T)+2)%3, (T)+2); \
    GCOMP((T)%3); }

  GSTAGE(0, 0); GSTAGE(1, 1);
  GSTEP(0, 4)  GSTEP(1, 4)  GSTEP(2, 4)  GSTEP(3, 4)
  GSTEP(4, 4)  GSTEP(5, 4)  GSTEP(6, 4)  GSTEP(7, 4)
  GSTEP(8, 4)  GSTEP(9, 4)  GSTEP(10, 4) GSTEP(11, 4)
  GSTEP(12, 4) GSTEP(13, 4) GSTEP(14, 4) GSTEP(15, 0)
#undef GSTAGE
#undef GCOMP
#undef GSTEP

  #pragma unroll
  for (int mt = 0; mt < 4; ++mt)
    #pragma unroll
    for (int nt = 0; nt < 4; ++nt)
      #pragma unroll
      for (int r = 0; r < 4; ++r){
        int row = m0 + wr*64 + mt*16 + lk*4 + r;
        int col = n0 + wc*64 + nt*16 + lr;
        out[(size_t)row*C_ + col] = acc[mt][nt][r] + bias[col];
      }
}

extern "C" void kernel_launch(void* const* d_in, const int* in_sizes, int n_in,
                              void* d_out, int out_size, void* d_ws, size_t ws_size,
                              hipStream_t stream){
  const float* x  = (const float*)d_in[0];
  const float* y0 = (const float*)d_in[1];
  const float* y1 = (const float*)d_in[2];
  const float* y2 = (const float*)d_in[3];
  const float* Wq = (const float*)d_in[4];
  const float* bq = (const float*)d_in[5];
  const float* Wk = (const float*)d_in[6];
  const float* bk = (const float*)d_in[7];
  const float* Wv = (const float*)d_in[8];
  const float* bv = (const float*)d_in[9];
  const float* Wo = (const float*)d_in[10];
  const float* bo = (const float*)d_in[11];

  char* ws = (char*)d_ws;
  size_t off = 0;
  auto alloc = [&](size_t bytes)->char*{
    char* p = ws + off; off += (bytes + 1023) & ~((size_t)1023); return p;
  };
  unsigned short* wqb   = (unsigned short*)alloc((size_t)C_*C_*2);
  unsigned short* wkb   = (unsigned short*)alloc((size_t)3*C_*C_*2);
  unsigned short* wvb   = (unsigned short*)alloc((size_t)3*C_*C_*2);
  unsigned short* wob   = (unsigned short*)alloc((size_t)C_*C_*2);
  unsigned short* qb    = (unsigned short*)alloc((size_t)M1_*C_*2);
  unsigned short* kbT   = (unsigned short*)alloc((size_t)3*B_*C_*T2_*2);
  unsigned short* vbT   = (unsigned short*)alloc((size_t)3*B_*C_*T2_*2);
  float*          ksum  = (float*)alloc((size_t)3*B_*C_*4);
  float*          part  = (float*)alloc((size_t)3*8*32*4096*4);
  unsigned short* ctxTb = (unsigned short*)alloc((size_t)3*32*4096*2);
  unsigned short* omid  = (unsigned short*)alloc((size_t)M1_*C_*2);

  (void)hipMemsetAsync(ksum, 0, (size_t)3*B_*C_*4, stream);

  // weights-only convert (~1.5 MB)
  cvt_bf16_4<<<dim3(3*C_*C_/4/256, 4), 256, 0, stream>>>(
      Wq, Wk, Wv, Wo, wqb, wkb, wvb, wob,
      C_*C_/4, 3*C_*C_/4, 3*C_*C_/4, C_*C_/4);

  proj<<<2048, 256, 0, stream>>>(x, y0, y1, y2, wqb, wkb, wvb, bq, bk, bv, qb, kbT, vbT, ksum);
  ctx_mfma<<<dim3(32, 8, 3), 256, 0, stream>>>(kbT, vbT, part);
  ctx_reduce<<<dim3(32, 3), 256, 0, stream>>>(part, ctxTb);
  combine<<<512, 256, 0, stream>>>(qb, ctxTb, ksum, omid);
  gemm_bt<<<512, 256, 0, stream>>>(omid, wob, bo, (float*)d_out);
}

// Round 18
// 123.590 us; speedup vs baseline: 1.1227x; 1.0354x over previous
//
#include <hip/hip_runtime.h>
#include <stdint.h>

#define B_ 4
#define T1_ 4096
#define T2_ 2048
#define C_ 512
#define H_ 8
#define D_ 64
#define M1_ (B_*T1_)   // 16384
#define M2_ (B_*T2_)   // 8192

using f32x4 = __attribute__((ext_vector_type(4))) float;
using bf16x8 = __attribute__((ext_vector_type(8))) __bf16;
using us8 = __attribute__((ext_vector_type(8))) unsigned short;
using us4 = __attribute__((ext_vector_type(4))) unsigned short;

__device__ __forceinline__ unsigned short f2bf(float f){
  unsigned int u = __builtin_bit_cast(unsigned int, f);
  unsigned int r = (u + 0x7fffu + ((u >> 16) & 1u)) >> 16;
  return (unsigned short)r;
}
__device__ __forceinline__ float bf2f(unsigned short u){
  return __builtin_bit_cast(float, ((unsigned int)u) << 16);
}
__device__ __forceinline__ f32x4 mfma16(us8 a, us8 b, f32x4 c){
  return __builtin_amdgcn_mfma_f32_16x16x32_bf16(
      __builtin_bit_cast(bf16x8, a), __builtin_bit_cast(bf16x8, b), c, 0, 0, 0);
}
// hot-path cvt: compiler emits packed v_cvt (m240: prefer cast over hand-asm)
__device__ __forceinline__ us8 cvt8(f32x4 a, f32x4 b){
  us8 v;
  #pragma unroll
  for (int j = 0; j < 4; ++j){
    v[j]   = __builtin_bit_cast(unsigned short, (__bf16)a[j]);
    v[4+j] = __builtin_bit_cast(unsigned short, (__bf16)b[j]);
  }
  return v;
}

typedef const __attribute__((address_space(1))) unsigned int gu32;
typedef __attribute__((address_space(3))) unsigned int lu32;
__device__ __forceinline__ void gl_lds16(const void* g, void* l){
  __builtin_amdgcn_global_load_lds((gu32*)g, (lu32*)l, 16, 0, 0);
}

#define WAIT_VM(N) asm volatile("s_waitcnt vmcnt(" #N ")" ::: "memory")
#define WAIT_LGKM() asm volatile("s_waitcnt lgkmcnt(0)" ::: "memory")
#define RAW_BAR()  { __builtin_amdgcn_s_barrier(); __builtin_amdgcn_sched_barrier(0); }

// chunk swizzle for the K-loop staging (involution, rule 21)
__device__ __forceinline__ int swz(int row, int blk){ return blk ^ ((row >> 1) & 3); }

// ---------------- fp32 -> bf16 convert (weights only) ----------------
__global__ __launch_bounds__(256) void cvt_bf16_4(const float* __restrict__ p0, const float* __restrict__ p1,
                                                  const float* __restrict__ p2, const float* __restrict__ p3,
                                                  unsigned short* o0, unsigned short* o1,
                                                  unsigned short* o2, unsigned short* o3,
                                                  int n0, int n1, int n2, int n3){
  const float* in; unsigned short* out; int n4;
  switch (blockIdx.y){
    case 0: in = p0; out = o0; n4 = n0; break;
    case 1: in = p1; out = o1; n4 = n1; break;
    case 2: in = p2; out = o2; n4 = n2; break;
    default: in = p3; out = o3; n4 = n3; break;
  }
  int i = blockIdx.x * 256 + threadIdx.x;
  if (i >= n4) return;
  f32x4 v = ((const f32x4*)in)[i];
  us4 o;
  #pragma unroll
  for (int j = 0; j < 4; ++j) o[j] = f2bf(v[j]);
  ((us4*)out)[i] = o;
}

// ---------- C-layout fp32 vals -> swizzled bf16 LDS tile -> coalesced store ----------
__device__ __forceinline__ void tile_write(unsigned short* tile, const f32x4 (&vals)[4][4],
                                           int wr, int wc, int lr, int lk){
  #pragma unroll
  for (int mt = 0; mt < 4; ++mt)
    #pragma unroll
    for (int nt = 0; nt < 4; ++nt)
      #pragma unroll
      for (int r = 0; r < 4; ++r){
        int row = wr*64 + mt*16 + lk*4 + r;
        int cb  = (wc*128 + nt*32 + lr*2) ^ ((row & 7) << 4);
        *(unsigned short*)((char*)tile + row*256 + cb) = f2bf(vals[mt][nt][r]);
      }
}
// transposed write: value for output (row=ch, col=n) -> tile[ch][n] (same swizzle family)
__device__ __forceinline__ void tile_write_T(unsigned short* tile, const f32x4 (&vals)[4][4],
                                             int wr, int wc, int lr, int lk){
  #pragma unroll
  for (int mt = 0; mt < 4; ++mt)
    #pragma unroll
    for (int nt = 0; nt < 4; ++nt)
      #pragma unroll
      for (int r = 0; r < 4; ++r){
        int n  = wr*64 + mt*16 + lk*4 + r;     // output column (time index)
        int ch = wc*64 + nt*16 + lr;           // output row (channel)
        int cb = (n*2) ^ ((ch & 7) << 4);
        *(unsigned short*)((char*)tile + ch*256 + cb) = f2bf(vals[mt][nt][r]);
      }
}
__device__ __forceinline__ void tile_flush(const unsigned short* tile, unsigned short* g,
                                           size_t row0, int col0, int ldg, int t){
  #pragma unroll
  for (int p = 0; p < 8; ++p){
    int row = p*16 + (t >> 4);
    int cb  = ((t & 15) * 16) ^ ((row & 7) << 4);
    us8 v = *(const us8*)((const char*)tile + row*256 + cb);
    *(us8*)(g + (row0 + row) * (size_t)ldg + col0 + (t & 15) * 8) = v;
  }
}

// ================= merged projection kernel (fp32 A reg-staged + cvt, bf16 W via gl_lds) =========
__global__ __launch_bounds__(256, 3) void proj(const float* __restrict__ xf,
                                               const float* __restrict__ y0f,
                                               const float* __restrict__ y1f,
                                               const float* __restrict__ y2f,
                                               const unsigned short* __restrict__ wqb,
                                               const unsigned short* __restrict__ wkb,
                                               const unsigned short* __restrict__ wvb,
                                               const float* __restrict__ bq,
                                               const float* __restrict__ bk,
                                               const float* __restrict__ bv,
                                               unsigned short* __restrict__ qb,
                                               unsigned short* __restrict__ kbT,
                                               unsigned short* __restrict__ vbT,
                                               float* __restrict__ ksum){
  __shared__ unsigned short smem[24576];       // 48 KB
  const int hw = blockIdx.x;
  const int work = (hw & 7) * 256 + (hw >> 3); // XCD-chunked bijective swizzle
  int seg, ii, m0, n0;
  const float* Af;
  const unsigned short* W;
  const float* bias;
  if (work < 512){
    seg = 0; ii = 0;
    m0 = (work >> 2) << 7; n0 = (work & 3) << 7;
    Af = xf; W = wqb; bias = bq;
  } else {
    int r = work - 512;
    int g = r >> 3, s = r & 7;
    ii = g >> 6; m0 = (g & 63) << 7;
    seg = (s < 4) ? 1 : 2;
    n0 = (s & 3) << 7;
    Af = (ii == 0) ? y0f : (ii == 1 ? y1f : y2f);
    W = (seg == 1 ? wkb : wvb) + (size_t)ii*C_*C_;
    bias = (seg == 1 ? bk : bv) + (size_t)ii*C_;
  }
  const int t = threadIdx.x;
  const int w = t >> 6, l = t & 63;
  const int wr = w >> 1, wc = w & 1;
  const int lr = l & 15, lk = l >> 4;
  const int row0 = t >> 2,          b0 = t & 3;
  const int row1 = (t + 256) >> 2,  b1 = t & 3;
  f32x4 acc[4][4] = {};
  f32x4 ar0[4], ar1[4];

#define LOADA(AR, TT) { \
    const float* ap0 = Af + (size_t)(m0+row0)*C_ + (TT)*32 + b0*8; \
    const float* ap1 = Af + (size_t)(m0+row1)*C_ + (TT)*32 + b1*8; \
    AR[0] = *(const f32x4*)ap0; AR[1] = *(const f32x4*)(ap0 + 4); \
    AR[2] = *(const f32x4*)ap1; AR[3] = *(const f32x4*)(ap1 + 4); }
#define DSWA(AR, BUF) { \
    *(us8*)&smem[(BUF)*4096 + row0*32 + swz(row0,b0)*8] = cvt8(AR[0], AR[1]); \
    *(us8*)&smem[(BUF)*4096 + row1*32 + swz(row1,b1)*8] = cvt8(AR[2], AR[3]); }
#define GLW(BUF, TT) { \
    int c=t, row=c>>2; \
    gl_lds16(W + (size_t)(n0+row)*C_ + (TT)*32 + swz(row,c&3)*8, &smem[12288+(BUF)*4096 + c*8]); \
    c=t+256; row=c>>2; \
    gl_lds16(W + (size_t)(n0+row)*C_ + (TT)*32 + swz(row,c&3)*8, &smem[12288+(BUF)*4096 + c*8]); }
#define PCOMP(S, WB) { \
    const unsigned short* sA = &smem[(S)*4096]; \
    const unsigned short* sW = &smem[12288 + (WB)*4096]; \
    us8 af[4], bfr[4]; \
    _Pragma("unroll") \
    for (int mt = 0; mt < 4; ++mt){ int R = wr*64 + mt*16 + lr; af[mt] = *(const us8*)&sA[R*32 + swz(R, lk)*8]; } \
    _Pragma("unroll") \
    for (int nt = 0; nt < 4; ++nt){ int R = wc*64 + nt*16 + lr; bfr[nt] = *(const us8*)&sW[R*32 + swz(R, lk)*8]; } \
    __builtin_amdgcn_s_setprio(1); \
    _Pragma("unroll") \
    for (int mt = 0; mt < 4; ++mt) \
      _Pragma("unroll") \
      for (int nt = 0; nt < 4; ++nt) \
        acc[mt][nt] = mfma16(af[mt], bfr[nt], acc[mt][nt]); \
    __builtin_amdgcn_s_setprio(0); }
// steady-state: enter with [A(T+1)x4, W(T+1)x2] outstanding (6)
#define PSTEP(T, ARW, ARL) { \
    WAIT_VM(2); \
    DSWA(ARW, ((T)+1)%3); \
    LOADA(ARL, (T)+2); \
    GLW(((T)+2)%3, (T)+2); \
    PCOMP((T)%3, (T)%3); \
    WAIT_LGKM(); \
    WAIT_VM(6); \
    RAW_BAR(); }

  LOADA(ar0, 0); GLW(0, 0);
  LOADA(ar1, 1); GLW(1, 1);
  WAIT_VM(8);            // A(0) regs ready
  DSWA(ar0, 0);
  WAIT_LGKM();
  WAIT_VM(6);            // W(0) drained -> visible after barrier
  RAW_BAR();
  PSTEP(0,  ar1, ar0) PSTEP(1,  ar0, ar1) PSTEP(2,  ar1, ar0) PSTEP(3,  ar0, ar1)
  PSTEP(4,  ar1, ar0) PSTEP(5,  ar0, ar1) PSTEP(6,  ar1, ar0) PSTEP(7,  ar0, ar1)
  PSTEP(8,  ar1, ar0) PSTEP(9,  ar0, ar1) PSTEP(10, ar1, ar0) PSTEP(11, ar0, ar1)
  PSTEP(12, ar1, ar0) PSTEP(13, ar0, ar1)
  { // step 14: no more loads
    WAIT_VM(2);
    DSWA(ar1, 0);        // tile 15 -> bufA 0
    PCOMP(2, 2);
    WAIT_LGKM();
    WAIT_VM(0);          // W(15) drained
    RAW_BAR();
  }
  PCOMP(0, 0);           // step 15
#undef LOADA
#undef DSWA
#undef GLW
#undef PCOMP
#undef PSTEP

  // bias
  {
    float bc[4];
    #pragma unroll
    for (int nt = 0; nt < 4; ++nt) bc[nt] = bias[n0 + wc*64 + nt*16 + lr];
    #pragma unroll
    for (int mt = 0; mt < 4; ++mt)
      #pragma unroll
      for (int nt = 0; nt < 4; ++nt)
        #pragma unroll
        for (int r = 0; r < 4; ++r) acc[mt][nt][r] += bc[nt];
  }
  if (seg <= 1){
    // in-register softmax over the wave's 64-col head group
    #pragma unroll
    for (int mt = 0; mt < 4; ++mt)
      #pragma unroll
      for (int r = 0; r < 4; ++r){
        float m = fmaxf(fmaxf(acc[mt][0][r], acc[mt][1][r]), fmaxf(acc[mt][2][r], acc[mt][3][r]));
        #pragma unroll
        for (int s = 1; s < 16; s <<= 1) m = fmaxf(m, __shfl_xor(m, s, 64));
        float sum = 0.f;
        #pragma unroll
        for (int nt = 0; nt < 4; ++nt){
          float e = __expf(acc[mt][nt][r] - m);
          acc[mt][nt][r] = e; sum += e;
        }
        #pragma unroll
        for (int s = 1; s < 16; s <<= 1) sum += __shfl_xor(sum, s, 64);
        float inv = 1.0f / sum;
        #pragma unroll
        for (int nt = 0; nt < 4; ++nt) acc[mt][nt][r] *= inv;
      }
  }
  if (seg == 1){
    // colsum -> ksum atomics
    const int b = m0 >> 11;
    #pragma unroll
    for (int nt = 0; nt < 4; ++nt){
      float cs = 0.f;
      #pragma unroll
      for (int mt = 0; mt < 4; ++mt)
        #pragma unroll
        for (int r = 0; r < 4; ++r) cs += acc[mt][nt][r];
      cs += __shfl_xor(cs, 16, 64);
      cs += __shfl_xor(cs, 32, 64);
      if (lk == 0)
        atomicAdd(&ksum[((size_t)ii*B_ + b)*C_ + n0 + wc*64 + nt*16 + lr], cs);
    }
  }
  __syncthreads();
  if (seg == 0){
    tile_write(smem, acc, wr, wc, lr, lk);
    __syncthreads();
    tile_flush(smem, qb, m0, n0, C_, t);
  } else {
    tile_write_T(smem, acc, wr, wc, lr, lk);
    __syncthreads();
    const int b = m0 >> 11;
    const int n_base = m0 & 2047;
    unsigned short* gT = (seg == 1 ? kbT : vbT);
    tile_flush(smem, gT, ((size_t)ii*B_ + b)*C_ + n0, n_base, T2_, t);
  }
}

// ================= ctx via MFMA (two-stage split-K=4): part -> reduce =================
__global__ __launch_bounds__(256) void ctx_mfma(const unsigned short* __restrict__ kbT,
                                                const unsigned short* __restrict__ vbT,
                                                float* __restrict__ part){
  const int bh = blockIdx.x, kc = blockIdx.y, i = blockIdx.z;
  const int b = bh >> 3, h = bh & 7;
  const size_t rowbase = ((size_t)i*B_ + b)*C_ + h*64;
  const unsigned short* kT = kbT + rowbase*T2_;
  const unsigned short* vT = vbT + rowbase*T2_;
  const int t = threadIdx.x;
  const int w = t >> 6, l = t & 63;
  const int qr = w >> 1, qc = w & 1;     // 32x32 quadrant per wave
  const int lr = l & 15, lk = l >> 4;
  const int n00 = kc * 512;
  f32x4 acc[2][2] = {};
  #pragma unroll
  for (int it = 0; it < 16; ++it){
    const int k0 = n00 + it*32 + lk*8;
    us8 a0 = *(const us8*)(kT + (size_t)(qr*32 +      lr)*T2_ + k0);
    us8 a1 = *(const us8*)(kT + (size_t)(qr*32 + 16 + lr)*T2_ + k0);
    us8 b0 = *(const us8*)(vT + (size_t)(qc*32 +      lr)*T2_ + k0);
    us8 b1 = *(const us8*)(vT + (size_t)(qc*32 + 16 + lr)*T2_ + k0);
    acc[0][0] = mfma16(a0, b0, acc[0][0]);
    acc[0][1] = mfma16(a0, b1, acc[0][1]);
    acc[1][0] = mfma16(a1, b0, acc[1][0]);
    acc[1][1] = mfma16(a1, b1, acc[1][1]);
  }
  float* dst = part + (((size_t)i*4 + kc)*32 + bh)*4096;
  #pragma unroll
  for (int fa = 0; fa < 2; ++fa)
    #pragma unroll
    for (int fb = 0; fb < 2; ++fb){
      int d0 = qr*32 + fa*16 + lk*4;
      int e  = qc*32 + fb*16 + lr;
      *(f32x4*)(dst + e*64 + d0) = acc[fa][fb];
    }
}

__global__ __launch_bounds__(256) void ctx_reduce(const float* __restrict__ part,
                                                  unsigned short* __restrict__ ctxTb){
  const int bh = blockIdx.x, i = blockIdx.y, t = threadIdx.x;
  for (int idx4 = t; idx4 < 1024; idx4 += 256){
    f32x4 s = {};
    #pragma unroll
    for (int kc = 0; kc < 4; ++kc){
      f32x4 v = *(const f32x4*)(part + (((size_t)i*4 + kc)*32 + bh)*4096 + idx4*4);
      #pragma unroll
      for (int j = 0; j < 4; ++j) s[j] += v[j];
    }
    us4 o;
    #pragma unroll
    for (int j = 0; j < 4; ++j) o[j] = f2bf(s[j]);
    *(us4*)(ctxTb + ((size_t)i*32 + bh)*4096 + idx4*4) = o;
  }
}

// ================= combine: omid = q + sum_i (q @ ctx_i) * Dinv_i =================
__global__ __launch_bounds__(256) void combine(const unsigned short* __restrict__ qb,
                                               const unsigned short* __restrict__ ctxTb,
                                               const float* __restrict__ ksum,
                                               unsigned short* __restrict__ omid){
  __shared__ unsigned short tile[128*128];
  const int hw = blockIdx.x;
  const int work = (hw & 7) * 64 + (hw >> 3);
  const int m0 = (work & 127) << 7, n0 = (work >> 7) << 7;
  const int t = threadIdx.x;
  const int w = t >> 6, l = t & 63;
  const int wr = w >> 1, wc = w & 1;
  const int lr = l & 15, lk = l >> 4;
  const int b = m0 >> 12;
  const int bh = b*8 + (n0 >> 6) + wc;
  #pragma unroll
  for (int p = 0; p < 8; ++p){
    int idx = p*256 + t;
    int row = idx >> 4, ch = idx & 15;
    gl_lds16(qb + (size_t)(m0+row)*C_ + n0 + (ch ^ (row & 7))*8, &tile[idx*8]);
  }
  WAIT_VM(0);
  __syncthreads();
  us8 afr[4][2];
  #pragma unroll
  for (int mt = 0; mt < 4; ++mt)
    #pragma unroll
    for (int kk = 0; kk < 2; ++kk){
      int row = wr*64 + mt*16 + lr;
      int ch = wc*8 + kk*4 + lk;
      afr[mt][kk] = *(const us8*)((const char*)tile + row*256 + ((ch ^ (row & 7)) << 4));
    }
  f32x4 acc[4][4];
  #pragma unroll
  for (int mt = 0; mt < 4; ++mt)
    #pragma unroll
    for (int nt = 0; nt < 4; ++nt)
      #pragma unroll
      for (int r = 0; r < 4; ++r){
        int row = wr*64 + mt*16 + lk*4 + r;
        int cbyte = wc*128 + nt*32 + lr*2;
        int ch = cbyte >> 4;
        unsigned short v = *(const unsigned short*)((const char*)tile + row*256 +
                            ((ch ^ (row & 7)) << 4) + (cbyte & 15));
        acc[mt][nt][r] = bf2f(v);
      }
  us8 bden[2];
  #pragma unroll
  for (int kk = 0; kk < 2; ++kk){
    us8 tmp = {};
    if (lr < 3){
      const float* kp = ksum + ((size_t)lr*B_ + b)*C_ + n0 + wc*64 + kk*32 + lk*8;
      f32x4 c0 = *(const f32x4*)kp;
      f32x4 c1 = *(const f32x4*)(kp + 4);
      #pragma unroll
      for (int j = 0; j < 4; ++j){ tmp[j] = f2bf(c0[j]); tmp[4+j] = f2bf(c1[j]); }
    }
    bden[kk] = tmp;
  }
  f32x4 den[4] = {};
  #pragma unroll
  for (int mt = 0; mt < 4; ++mt)
    #pragma unroll
    for (int kk = 0; kk < 2; ++kk)
      den[mt] = mfma16(afr[mt][kk], bden[kk], den[mt]);
  #pragma unroll 1
  for (int i = 0; i < 3; ++i){
    f32x4 dinv[4];
    #pragma unroll
    for (int mt = 0; mt < 4; ++mt)
      #pragma unroll
      for (int r = 0; r < 4; ++r)
        dinv[mt][r] = 1.0f / (__shfl(den[mt][r], (l & 48) | i, 64) + 1e-8f);
    #pragma unroll
    for (int nt = 0; nt < 4; ++nt){
      us8 bfr[2];
      #pragma unroll
      for (int kk = 0; kk < 2; ++kk)
        bfr[kk] = *(const us8*)(ctxTb + ((size_t)(i*32 + bh))*4096 + (nt*16 + lr)*64 + kk*32 + lk*8);
      f32x4 p[4] = {};
      #pragma unroll
      for (int mt = 0; mt < 4; ++mt)
        #pragma unroll
        for (int kk = 0; kk < 2; ++kk)
          p[mt] = mfma16(afr[mt][kk], bfr[kk], p[mt]);
      #pragma unroll
      for (int mt = 0; mt < 4; ++mt)
        #pragma unroll
        for (int r = 0; r < 4; ++r)
          acc[mt][nt][r] += p[mt][r] * dinv[mt][r];
    }
  }
  __syncthreads();
  tile_write(tile, acc, wr, wc, lr, lk);
  __syncthreads();
  tile_flush(tile, omid, m0, n0, C_, t);
}

// ---------------- O-proj GEMM (3-buf, RACE-FREE depth-2 counted-vmcnt) ----------------
__global__ __launch_bounds__(256, 3) void gemm_bt(const unsigned short* __restrict__ A,
                                                  const unsigned short* __restrict__ Bw,
                                                  const float* __restrict__ bias,
                                                  float* __restrict__ out){
  __shared__ unsigned short smem[3*2*4096];
  const int hw = blockIdx.x;
  const int work = (hw & 7) * 64 + (hw >> 3);
  const int m0 = ((work >> 2) & 127) << 7, n0 = (work & 3) << 7;
  const int t = threadIdx.x;
  const int w = t >> 6, l = t & 63;
  const int wr = w >> 1, wc = w & 1;
  const int lr = l & 15, lk = l >> 4;
  f32x4 acc[4][4] = {};

#define GSTAGE(BB, TT) { \
    int c = t, row = c >> 2; \
    gl_lds16(A  + (size_t)(m0+row)*C_ + (TT)*32 + swz(row, c & 3)*8, &smem[(BB)*8192 + c*8]); \
    gl_lds16(Bw + (size_t)(n0+row)*C_ + (TT)*32 + swz(row, c & 3)*8, &smem[(BB)*8192 + 4096 + c*8]); \
    c = t + 256; row = c >> 2; \
    gl_lds16(A  + (size_t)(m0+row)*C_ + (TT)*32 + swz(row, c & 3)*8, &smem[(BB)*8192 + c*8]); \
    gl_lds16(Bw + (size_t)(n0+row)*C_ + (TT)*32 + swz(row, c & 3)*8, &smem[(BB)*8192 + 4096 + c*8]); }
#define GCOMP(BB) { \
    const unsigned short* sA = &smem[(BB)*8192]; \
    const unsigned short* sB = &smem[(BB)*8192 + 4096]; \
    us8 af[4], bfr[4]; \
    _Pragma("unroll") \
    for (int mt = 0; mt < 4; ++mt){ int R = wr*64 + mt*16 + lr; af[mt] = *(const us8*)&sA[R*32 + swz(R, lk)*8]; } \
    _Pragma("unroll") \
    for (int nt = 0; nt < 4; ++nt){ int R = wc*64 + nt*16 + lr; bfr[nt] = *(const us8*)&sB[R*32 + swz(R, lk)*8]; } \
    __builtin_amdgcn_s_setprio(1); \
    _Pragma("unroll") \
    for (int mt = 0; mt < 4; ++mt) \
      _Pragma("unroll") \
      for (int nt = 0; nt < 4; ++nt) \
        acc[mt][nt] = mfma16(af[mt], bfr[nt], acc[mt][nt]); \
    __builtin_amdgcn_s_setprio(0); }
#define GSTEP(T, N) { \
    WAIT_VM(N); \
    RAW_BAR(); \
    if ((T) + 2 < 16) GSTAGE(((T)+2)%3, (T)+2); \
    GCOMP((T)%3); }

  GSTAGE(0, 0); GSTAGE(1, 1);
  GSTEP(0, 4)  GSTEP(1, 4)  GSTEP(2, 4)  GSTEP(3, 4)
  GSTEP(4, 4)  GSTEP(5, 4)  GSTEP(6, 4)  GSTEP(7, 4)
  GSTEP(8, 4)  GSTEP(9, 4)  GSTEP(10, 4) GSTEP(11, 4)
  GSTEP(12, 4) GSTEP(13, 4) GSTEP(14, 4) GSTEP(15, 0)
#undef GSTAGE
#undef GCOMP
#undef GSTEP

  #pragma unroll
  for (int mt = 0; mt < 4; ++mt)
    #pragma unroll
    for (int nt = 0; nt < 4; ++nt)
      #pragma unroll
      for (int r = 0; r < 4; ++r){
        int row = m0 + wr*64 + mt*16 + lk*4 + r;
        int col = n0 + wc*64 + nt*16 + lr;
        out[(size_t)row*C_ + col] = acc[mt][nt][r] + bias[col];
      }
}

extern "C" void kernel_launch(void* const* d_in, const int* in_sizes, int n_in,
                              void* d_out, int out_size, void* d_ws, size_t ws_size,
                              hipStream_t stream){
  const float* x  = (const float*)d_in[0];
  const float* y0 = (const float*)d_in[1];
  const float* y1 = (const float*)d_in[2];
  const float* y2 = (const float*)d_in[3];
  const float* Wq = (const float*)d_in[4];
  const float* bq = (const float*)d_in[5];
  const float* Wk = (const float*)d_in[6];
  const float* bk = (const float*)d_in[7];
  const float* Wv = (const float*)d_in[8];
  const float* bv = (const float*)d_in[9];
  const float* Wo = (const float*)d_in[10];
  const float* bo = (const float*)d_in[11];

  char* ws = (char*)d_ws;
  size_t off = 0;
  auto alloc = [&](size_t bytes)->char*{
    char* p = ws + off; off += (bytes + 1023) & ~((size_t)1023); return p;
  };
  unsigned short* wqb   = (unsigned short*)alloc((size_t)C_*C_*2);
  unsigned short* wkb   = (unsigned short*)alloc((size_t)3*C_*C_*2);
  unsigned short* wvb   = (unsigned short*)alloc((size_t)3*C_*C_*2);
  unsigned short* wob   = (unsigned short*)alloc((size_t)C_*C_*2);
  unsigned short* qb    = (unsigned short*)alloc((size_t)M1_*C_*2);
  unsigned short* kbT   = (unsigned short*)alloc((size_t)3*B_*C_*T2_*2);
  unsigned short* vbT   = (unsigned short*)alloc((size_t)3*B_*C_*T2_*2);
  float*          ksum  = (float*)alloc((size_t)3*B_*C_*4);
  float*          part  = (float*)alloc((size_t)3*4*32*4096*4);
  unsigned short* ctxTb = (unsigned short*)alloc((size_t)3*32*4096*2);
  unsigned short* omid  = (unsigned short*)alloc((size_t)M1_*C_*2);

  (void)hipMemsetAsync(ksum, 0, (size_t)3*B_*C_*4, stream);

  // weights-only convert (~1.5 MB)
  cvt_bf16_4<<<dim3(3*C_*C_/4/256, 4), 256, 0, stream>>>(
      Wq, Wk, Wv, Wo, wqb, wkb, wvb, wob,
      C_*C_/4, 3*C_*C_/4, 3*C_*C_/4, C_*C_/4);

  proj<<<2048, 256, 0, stream>>>(x, y0, y1, y2, wqb, wkb, wvb, bq, bk, bv, qb, kbT, vbT, ksum);
  ctx_mfma<<<dim3(32, 4, 3), 256, 0, stream>>>(kbT, vbT, part);
  ctx_reduce<<<dim3(32, 3), 256, 0, stream>>>(part, ctxTb);
  combine<<<512, 256, 0, stream>>>(qb, ctxTb, ksum, omid);
  gemm_bt<<<512, 256, 0, stream>>>(omid, wob, bo, (float*)d_out);
}